// Round 11
// baseline (225.902 us; speedup 1.0000x reference)
//
#include <hip/hip_runtime.h>
#include <hip/hip_bf16.h>
#include <stdint.h>

// StrideGraphSAGE on MI355X (gfx950).
// h_l = elu(agg @ Wl[l] + bl[l] + nodes @ Wr[l]); out = concat(h_0..h_3, x) along C.
// agg is nonzero only for rows < 1089; edge set = deterministic stride-2 grid.
//
// R11: B-IN-REGISTERS GEMM. Diagnosis: all prior structures were LDS-read-pipe
// bound (96 KB/CU/K-step; ds_read_b128 ~85B/cyc => ~64us). Fix: B strip lives
// in 128 VGPRs per wave (bv[8][4], K=256 x 64 cols), LDS carries A only
// (3-ring, 8KB slices, counted vmcnt(2)) -> 32 KB/CU/step. Block = fixed
// 128-col strip, loops over ~9 brow tiles; A-prefetch continuous across jobs.
// Grid 512 = 8 strips x 64 slots = exactly 2 blocks/CU; brow-partners share
// an XCD ((strip*64+bs)&7 = bs&7). Mixed rows (bs<9) add one agg@WlT pass
// with per-step global B loads (L2-hot).

#define C_DIM 256
#define GRID_G 33
#define N_NODES 1089
#define BATCH 64
#define TOTAL (BATCH * N_NODES)     // 69696
#define M_PAD 69760
#define CN (C_DIM * N_NODES)        // 278784
#define OUT_STRIDE_B (5 * CN)       // 1393920
#define NCOLS 1024
#define AGG_ROWS 1152               // 9 tiles of 128; rows 1089..1151 zeroed

using bf16 = __hip_bfloat16;
typedef __attribute__((ext_vector_type(8))) short short8;
typedef __attribute__((ext_vector_type(4))) float f32x4;

// ---- workspace layout (bytes) ----
#define NODES_BYTES ((size_t)M_PAD * C_DIM * 2)
#define OFF_NODES   ((size_t)0)
#define OFF_AGGB    (NODES_BYTES)
#define AGGB_BYTES  ((size_t)AGG_ROWS * C_DIM * 2)
#define OFF_WLT     (OFF_AGGB + AGGB_BYTES)
#define WT_BYTES    ((size_t)NCOLS * C_DIM * 2)
#define OFF_WRT     (OFF_WLT + WT_BYTES)

__device__ __forceinline__ void gload16(void* lds, const void* g) {
    __builtin_amdgcn_global_load_lds(
        (const __attribute__((address_space(1))) uint32_t*)g,
        (__attribute__((address_space(3))) uint32_t*)lds,
        16, 0, 0);
}

// ---- fused prep: blocks 0..127 W->WT bf16; 128..1279: x -> nodes + out block 4 ----
__global__ __launch_bounds__(256)
void prep_kernel(const float* __restrict__ x,
                 const float* __restrict__ Wl, const float* __restrict__ Wr,
                 bf16* __restrict__ nodes, bf16* __restrict__ WlT, bf16* __restrict__ WrT,
                 float* __restrict__ out)
{
    __shared__ char smem[33792];
    const int t = threadIdx.x;
    const int bid = blockIdx.x;
    if (bid < 128) {
        float (*tile)[65] = (float(*)[65])smem;
        const int sel = bid & 1;
        const int l = (bid >> 1) & 3;
        const int kt = ((bid >> 3) & 3) * 64;
        const int ct = ((bid >> 5) & 3) * 64;
        const float* W = sel ? Wr : Wl;
        bf16* WT = sel ? WrT : WlT;
        const int tc = t & 63;
        const int tk = t >> 6;
#pragma unroll
        for (int i = 0; i < 16; ++i) {
            int kl = i * 4 + tk;
            tile[kl][tc] = W[((size_t)(l * 256 + kt + kl)) * 256 + ct + tc];
        }
        __syncthreads();
#pragma unroll
        for (int i = 0; i < 16; ++i) {
            int cl = i * 4 + tk;
            WT[((size_t)(l * 256 + ct + cl)) * 256 + kt + tc] = __float2bfloat16(tile[tc][cl]);
        }
    } else {
        bf16 (*tile)[66] = (bf16(*)[66])smem;
        const int bid2 = bid - 128;
        const int b = bid2 / 18;
        const int n0 = (bid2 % 18) * 64;
        const int nl = t & 63;
        const int cs = t >> 6;
        const int n = n0 + nl;
        const bool nvalid = n < N_NODES;
        const float* xb = x + (size_t)b * CN;
        float* outb = out + (size_t)b * OUT_STRIDE_B + (size_t)4 * CN;
#pragma unroll 4
        for (int cc = 0; cc < 64; ++cc) {
            int c = cc * 4 + cs;
            if (nvalid) {
                float v = xb[(size_t)c * N_NODES + n];
                outb[(size_t)c * N_NODES + n] = v;
                tile[c][nl] = __float2bfloat16(v);
            }
        }
        __syncthreads();
        const int half = t >> 7;
        const int c0 = (t & 127) * 2;
#pragma unroll
        for (int it = 0; it < 32; ++it) {
            int row = it * 2 + half;
            int nr = n0 + row;
            if (nr < N_NODES) {
                __hip_bfloat162 p;
                p.x = tile[c0][row];
                p.y = tile[c0 + 1][row];
                *(__hip_bfloat162*)(nodes + ((size_t)b * N_NODES + nr) * C_DIM + c0) = p;
            }
        }
    }
}

// ---- analytic mean-aggregate; rows N_NODES..1151 zeroed ----
__global__ __launch_bounds__(256)
void gather_kernel(const bf16* __restrict__ nodes, bf16* __restrict__ aggb)
{
    const int n = blockIdx.x;        // 0..1151
    const int c = threadIdx.x;
    if (n >= N_NODES) {
        aggb[(size_t)n * C_DIM + c] = __float2bfloat16(0.f);
        return;
    }
    const int i = n / GRID_G, j = n % GRID_G;
    float s = 0.f, d = 0.f;
    if (j >= 2)           { s += __bfloat162float(nodes[(size_t)(n - 2)  * C_DIM + c]); d += 1.f; }
    if (i >= 2)           { s += __bfloat162float(nodes[(size_t)(n - 66) * C_DIM + c]); d += 1.f; }
    if (i >= 2 && j >= 2) { s += __bfloat162float(nodes[(size_t)(n - 68) * C_DIM + c]); d += 1.f; }
    if (i >= 2 && j >= 1 && j <= 30)
                          { s += __bfloat162float(nodes[(size_t)(n - 64) * C_DIM + c]); d += 1.f; }
    aggb[(size_t)n * C_DIM + c] = __float2bfloat16(d > 0.f ? s / d : 0.f);
}

// ---- B-in-registers GEMM ----
__global__ __launch_bounds__(256, 2)
void gemm_kernel(const bf16* __restrict__ nodes, const bf16* __restrict__ agg,
                 const bf16* __restrict__ WrT, const bf16* __restrict__ WlT,
                 const float* __restrict__ bias, float* __restrict__ out)
{
    __shared__ bf16 Ar[3][128 * 32];   // A-only ring, 8KB slices
    const int t = threadIdx.x;
    const int lane = t & 63;
    const int w = t >> 6;
    const int bs = (int)(blockIdx.x & 63);      // brow slot; bs&7 = XCD
    const int strip = (int)(blockIdx.x >> 6);   // 0..7 -> 128-col strip

    const int wr = (w >> 1) << 6;
    const int wc = (w & 1) << 6;
    const int fr = lane & 15;
    const int kq = lane >> 4;
    const int swzr = (kq ^ ((fr >> 1) & 3)) << 3;        // phys slot for reads (shorts)
    const int tq = t >> 2;
    const int kk = (((t & 3) ^ ((tq >> 1) & 3)) << 3);   // inverse-swizzled source slot
    const size_t stoff = (size_t)tq * C_DIM + kk;

    char* ArB = (char*)Ar;
    const short* ArS = (const short*)Ar;

    // ---- B strip into registers: bv[ks][nf] = WrT[col][ks*32 + kq*8 ..+8],
    //      col = strip*128 + wc + nf*16 + fr  (matches LDS-swizzle-read layout) ----
    const bf16* Bp = WrT + ((size_t)(strip * 128 + wc + fr)) * C_DIM + kq * 8;
    short8 bv[8][4];
#pragma unroll
    for (int ks = 0; ks < 8; ++ks)
#pragma unroll
        for (int nf = 0; nf < 4; ++nf)
            bv[ks][nf] = *(const short8*)(Bp + (size_t)nf * 16 * C_DIM + ks * 32);
    const bf16* Lp = WlT + ((size_t)(strip * 128 + wc + fr)) * C_DIM + kq * 8;

    const int nbrow = (bs < 33) ? 9 : 8;        // 545 = 64*8 + 33
    const bool hasMix = (bs < 9);               // extra agg@WlT pass at g=0
    const int nj = nbrow + (hasMix ? 1 : 0);

    f32x4 acc[4][4] = {};

    auto decode = [&](int j, int& brw, bool& isAgg) {
        if (hasMix) { isAgg = (j == 1); brw = (j <= 1) ? bs : bs + 64 * (j - 1); }
        else        { isAgg = false;    brw = bs + 64 * j; }
    };

    // prologue: job-0 slices 0,1 into bufs 0,1; publish
    {
        int brw0; bool a0; decode(0, brw0, a0);
        const bf16* A0 = nodes + (size_t)brw0 * 128 * C_DIM + stoff;
        gload16(ArB + 0 * 8192 + w * 1024,        A0);
        gload16(ArB + 0 * 8192 + 4096 + w * 1024, A0 + 64 * C_DIM);
        gload16(ArB + 1 * 8192 + w * 1024,        A0 + 32);
        gload16(ArB + 1 * 8192 + 4096 + w * 1024, A0 + 64 * C_DIM + 32);
    }
    asm volatile("s_waitcnt vmcnt(0)" ::: "memory");
    __builtin_amdgcn_s_barrier();

    int rb = 0;
    for (int j = 0; j < nj; ++j) {
        int brw; bool isAgg; decode(j, brw, isAgg);
        const bool doEpi = !(hasMix && j == 0);
        const bf16* Ac = (isAgg ? agg : nodes) + (size_t)brw * 128 * C_DIM + stoff;
        int brwN; bool aggN;
        if (j + 1 < nj) decode(j + 1, brwN, aggN); else { brwN = brw; aggN = isAgg; }
        const bf16* An = (aggN ? agg : nodes) + (size_t)brwN * 128 * C_DIM + stoff;

#pragma unroll
        for (int ss = 0; ss < 8; ++ss) {
            // steady state: stages f, f+1 outstanding -> drain f, keep f+1 in flight.
            // (post-epilogue this also lazily drains the older stores - correct, in-order)
            asm volatile("s_waitcnt vmcnt(2)" ::: "memory");
            __builtin_amdgcn_s_barrier();
            const int wb = (rb == 0) ? 2 : ((rb == 1) ? 0 : 1);
            if (ss < 6) {
                gload16(ArB + wb * 8192 + w * 1024,        Ac + (ss + 2) * 32);
                gload16(ArB + wb * 8192 + 4096 + w * 1024, Ac + 64 * C_DIM + (ss + 2) * 32);
            } else {   // prefetch next job's slices 0,1 (redundant re-read on last job)
                gload16(ArB + wb * 8192 + w * 1024,        An + (ss - 6) * 32);
                gload16(ArB + wb * 8192 + 4096 + w * 1024, An + 64 * C_DIM + (ss - 6) * 32);
            }
            short8 av[4];
#pragma unroll
            for (int m = 0; m < 4; ++m)
                av[m] = *(const short8*)(ArS + rb * 4096 + (wr + m * 16 + fr) * 32 + swzr);
            if (isAgg) {
                short8 bl[4];
#pragma unroll
                for (int nf = 0; nf < 4; ++nf)
                    bl[nf] = *(const short8*)(Lp + (size_t)nf * 16 * C_DIM + ss * 32);
#pragma unroll
                for (int m = 0; m < 4; ++m)
#pragma unroll
                    for (int n = 0; n < 4; ++n)
                        acc[m][n] = __builtin_amdgcn_mfma_f32_16x16x32_bf16(
                            av[m], bl[n], acc[m][n], 0, 0, 0);
            } else {
#pragma unroll
                for (int m = 0; m < 4; ++m)
#pragma unroll
                    for (int n = 0; n < 4; ++n)
                        acc[m][n] = __builtin_amdgcn_mfma_f32_16x16x32_bf16(
                            av[m], bv[ss][n], acc[m][n], 0, 0, 0);
            }
            rb = (rb == 2) ? 0 : rb + 1;
        }

        if (doEpi) {
            const int rq = kq * 4;
            const int r0 = brw * 128 + wr + rq;
            const unsigned bb0 = (unsigned)r0 / N_NODES;
            const int rsw = (int)((bb0 + 1) * N_NODES);
            const int colbase = strip * 128 + wc + fr;
            size_t coff[4];
            float bi[4];
#pragma unroll
            for (int n = 0; n < 4; ++n) {
                int col = colbase + n * 16;
                coff[n] = (size_t)(col >> 8) * CN + (col & 255);
                bi[n] = bias[col];
            }
#pragma unroll
            for (int m = 0; m < 4; ++m) {
#pragma unroll
                for (int reg = 0; reg < 4; ++reg) {
                    int r = r0 + m * 16 + reg;
                    if (r < TOTAL) {
                        int bb = (int)bb0 + (r >= rsw ? 1 : 0);
                        int nn = r - bb * N_NODES;
                        size_t base = (size_t)bb * OUT_STRIDE_B + (size_t)nn * C_DIM;
#pragma unroll
                        for (int n = 0; n < 4; ++n) {
                            float v = acc[m][n][reg] + bi[n];
                            v = v > 0.f ? v : (__expf(v) - 1.0f);
                            out[base + coff[n]] = v;
                        }
                    }
                }
            }
#pragma unroll
            for (int m = 0; m < 4; ++m)
#pragma unroll
                for (int n = 0; n < 4; ++n)
                    acc[m][n] = (f32x4){0.f, 0.f, 0.f, 0.f};
        }
    }
}

extern "C" void kernel_launch(void* const* d_in, const int* in_sizes, int n_in,
                              void* d_out, int out_size, void* d_ws, size_t ws_size,
                              hipStream_t stream) {
    const float* x  = (const float*)d_in[0];
    const float* Wl = (const float*)d_in[1];
    const float* bl = (const float*)d_in[2];
    const float* Wr = (const float*)d_in[3];
    float* out = (float*)d_out;
    char* ws = (char*)d_ws;

    bf16* nodes = (bf16*)(ws + OFF_NODES);
    bf16* aggb  = (bf16*)(ws + OFF_AGGB);
    bf16* WlT   = (bf16*)(ws + OFF_WLT);
    bf16* WrT   = (bf16*)(ws + OFF_WRT);

    prep_kernel<<<128 + BATCH * 18, 256, 0, stream>>>(x, Wl, Wr, nodes, WlT, WrT, out);
    gather_kernel<<<AGG_ROWS, 256, 0, stream>>>(nodes, aggb);
    gemm_kernel<<<512, 256, 0, stream>>>(nodes, aggb, WrT, WlT, bl, out);
}

// Round 12
// 138.657 us; speedup vs baseline: 1.6292x; 1.6292x over previous
//
#include <hip/hip_runtime.h>
#include <hip/hip_bf16.h>
#include <stdint.h>

// StrideGraphSAGE on MI355X (gfx950).
// h_l = elu(agg @ Wl[l] + bl[l] + nodes @ Wr[l]); out = concat(h_0..h_3, x) along C.
// agg is nonzero only for rows < 1089; edge set = deterministic stride-2 grid.
//
// R12 = R4 core (128^2, 3-ring, counted vmcnt(4), XCD swizzle) with ONE change:
// MFMA operands swapped -> acc f32x4 holds 4 CONSECUTIVE output columns
// (C/D map col=lane&15,row=(lane>>4)*4+reg; swapping operands transposes roles).
// Epilogue: 16x global_store_dwordx4 (nontemporal) per thread instead of 64x
// scalar dword -> 4x fewer store transactions, streaming past L2.

#define C_DIM 256
#define GRID_G 33
#define N_NODES 1089
#define BATCH 64
#define TOTAL (BATCH * N_NODES)     // 69696
#define M_PAD 69760
#define CN (C_DIM * N_NODES)        // 278784
#define OUT_STRIDE_B (5 * CN)       // 1393920
#define NCOLS 1024
#define AGG_ROWS 1152               // 9 tiles of 128; rows 1089..1151 zeroed

using bf16 = __hip_bfloat16;
typedef __attribute__((ext_vector_type(8))) short short8;
typedef __attribute__((ext_vector_type(4))) float f32x4;

// ---- workspace layout (bytes) ----
#define NODES_BYTES ((size_t)M_PAD * C_DIM * 2)
#define OFF_NODES   ((size_t)0)
#define OFF_AGGB    (NODES_BYTES)
#define AGGB_BYTES  ((size_t)AGG_ROWS * C_DIM * 2)
#define OFF_WLT     (OFF_AGGB + AGGB_BYTES)
#define WT_BYTES    ((size_t)NCOLS * C_DIM * 2)
#define OFF_WRT     (OFF_WLT + WT_BYTES)

__device__ __forceinline__ void gload16(void* lds, const void* g) {
    __builtin_amdgcn_global_load_lds(
        (const __attribute__((address_space(1))) uint32_t*)g,
        (__attribute__((address_space(3))) uint32_t*)lds,
        16, 0, 0);
}

// ---- fused prep: blocks 0..127 W->WT bf16; 128..1279: x -> nodes + out block 4 ----
__global__ __launch_bounds__(256)
void prep_kernel(const float* __restrict__ x,
                 const float* __restrict__ Wl, const float* __restrict__ Wr,
                 bf16* __restrict__ nodes, bf16* __restrict__ WlT, bf16* __restrict__ WrT,
                 float* __restrict__ out)
{
    __shared__ char smem[33792];
    const int t = threadIdx.x;
    const int bid = blockIdx.x;
    if (bid < 128) {
        float (*tile)[65] = (float(*)[65])smem;
        const int sel = bid & 1;
        const int l = (bid >> 1) & 3;
        const int kt = ((bid >> 3) & 3) * 64;
        const int ct = ((bid >> 5) & 3) * 64;
        const float* W = sel ? Wr : Wl;
        bf16* WT = sel ? WrT : WlT;
        const int tc = t & 63;
        const int tk = t >> 6;
#pragma unroll
        for (int i = 0; i < 16; ++i) {
            int kl = i * 4 + tk;
            tile[kl][tc] = W[((size_t)(l * 256 + kt + kl)) * 256 + ct + tc];
        }
        __syncthreads();
#pragma unroll
        for (int i = 0; i < 16; ++i) {
            int cl = i * 4 + tk;
            WT[((size_t)(l * 256 + ct + cl)) * 256 + kt + tc] = __float2bfloat16(tile[tc][cl]);
        }
    } else {
        bf16 (*tile)[66] = (bf16(*)[66])smem;
        const int bid2 = bid - 128;
        const int b = bid2 / 18;
        const int n0 = (bid2 % 18) * 64;
        const int nl = t & 63;
        const int cs = t >> 6;
        const int n = n0 + nl;
        const bool nvalid = n < N_NODES;
        const float* xb = x + (size_t)b * CN;
        float* outb = out + (size_t)b * OUT_STRIDE_B + (size_t)4 * CN;
#pragma unroll 4
        for (int cc = 0; cc < 64; ++cc) {
            int c = cc * 4 + cs;
            if (nvalid) {
                float v = xb[(size_t)c * N_NODES + n];
                __builtin_nontemporal_store(v, &outb[(size_t)c * N_NODES + n]);
                tile[c][nl] = __float2bfloat16(v);
            }
        }
        __syncthreads();
        const int half = t >> 7;
        const int c0 = (t & 127) * 2;
#pragma unroll
        for (int it = 0; it < 32; ++it) {
            int row = it * 2 + half;
            int nr = n0 + row;
            if (nr < N_NODES) {
                __hip_bfloat162 p;
                p.x = tile[c0][row];
                p.y = tile[c0 + 1][row];
                *(__hip_bfloat162*)(nodes + ((size_t)b * N_NODES + nr) * C_DIM + c0) = p;
            }
        }
    }
}

// ---- analytic mean-aggregate; rows N_NODES..1151 zeroed ----
__global__ __launch_bounds__(256)
void gather_kernel(const bf16* __restrict__ nodes, bf16* __restrict__ aggb)
{
    const int n = blockIdx.x;        // 0..1151
    const int c = threadIdx.x;
    if (n >= N_NODES) {
        aggb[(size_t)n * C_DIM + c] = __float2bfloat16(0.f);
        return;
    }
    const int i = n / GRID_G, j = n % GRID_G;
    float s = 0.f, d = 0.f;
    if (j >= 2)           { s += __bfloat162float(nodes[(size_t)(n - 2)  * C_DIM + c]); d += 1.f; }
    if (i >= 2)           { s += __bfloat162float(nodes[(size_t)(n - 66) * C_DIM + c]); d += 1.f; }
    if (i >= 2 && j >= 2) { s += __bfloat162float(nodes[(size_t)(n - 68) * C_DIM + c]); d += 1.f; }
    if (i >= 2 && j >= 1 && j <= 30)
                          { s += __bfloat162float(nodes[(size_t)(n - 64) * C_DIM + c]); d += 1.f; }
    aggb[(size_t)n * C_DIM + c] = __float2bfloat16(d > 0.f ? s / d : 0.f);
}

// ---- fused GEMM: out = elu(nodes@WrT^T + [agg@WlT^T] + bias), dwordx4 stores ----
// 128x128 tile, 4 waves, 16x16x32 bf16 MFMA. 3-buffer LDS, 2-deep prefetch,
// counted s_waitcnt vmcnt(4) + raw s_barrier. XOR-swizzled LDS both-sides.
// XCD-aware block swizzle. MFMA operands SWAPPED vs R4: acc[m][n] f32x4 =
// out[row = brow*128+wr+m*16+fr][cols = bcol*128+wc+n*16+kq*4 .. +3].
__global__ __launch_bounds__(256)
void gemm_kernel(const bf16* __restrict__ nodes, const bf16* __restrict__ agg,
                 const bf16* __restrict__ WrT, const bf16* __restrict__ WlT,
                 const float* __restrict__ bias, float* __restrict__ out)
{
    __shared__ bf16 Alds[3][128 * 32];
    __shared__ bf16 Blds[3][128 * 32];
    const int t = threadIdx.x;
    const int lane = t & 63;
    const int w = t >> 6;
    const unsigned bid = blockIdx.x;
    const unsigned swz = (bid & 7) * 545 + (bid >> 3);
    const int bcol = swz & 7;
    const int brow = swz >> 3;

    f32x4 acc[4][4] = {};

    // staging: phys 16B slot s holds logical slot s ^ ((row>>1)&3)
    const int tq = t >> 2;                               // rows 0..63 (+64 for issue 1)
    const int kk = (((t & 3) ^ ((tq >> 1) & 3)) << 3);
    const int wr = (w >> 1) << 6;
    const int wc = (w & 1) << 6;
    const int fr = lane & 15;
    const int kq = lane >> 4;
    const int swzr = (kq ^ ((fr >> 1) & 3)) << 3;        // phys slot for reads (shorts)

    char* AldsB = (char*)Alds;
    char* BldsB = (char*)Blds;
    const short* AldsS = (const short*)Alds;
    const short* BldsS = (const short*)Blds;

    const int nsteps = (brow * 128 < N_NODES) ? 16 : 8;
    const bf16* Abase0 = nodes + (size_t)brow * 128 * C_DIM;
    const bf16* Abase1 = agg + (size_t)brow * 128 * C_DIM;
    const bf16* Bbase0 = WrT + (size_t)bcol * 128 * C_DIM;
    const bf16* Bbase1 = WlT + (size_t)bcol * 128 * C_DIM;

    auto STAGE = [&](int s, int buf) {
        const int k0 = (s & 7) * 32;
        const bf16* Ag = (s < 8 ? Abase0 : Abase1) + (size_t)tq * C_DIM + k0 + kk;
        const bf16* Bg = (s < 8 ? Bbase0 : Bbase1) + (size_t)tq * C_DIM + k0 + kk;
        gload16(AldsB + buf * 8192 + w * 1024,        Ag);
        gload16(AldsB + buf * 8192 + 4096 + w * 1024, Ag + 64 * C_DIM);
        gload16(BldsB + buf * 8192 + w * 1024,        Bg);
        gload16(BldsB + buf * 8192 + 4096 + w * 1024, Bg + 64 * C_DIM);
    };

    STAGE(0, 0);
    STAGE(1, 1);                       // 8 vmem ops in flight
    int rb = 0;
    for (int s = 0; s < nsteps; ++s) {
        if (s + 1 < nsteps) asm volatile("s_waitcnt vmcnt(4)" ::: "memory");
        else                asm volatile("s_waitcnt vmcnt(0)" ::: "memory");
        __builtin_amdgcn_s_barrier();
        if (s + 2 < nsteps) STAGE(s + 2, rb == 0 ? 2 : (rb == 1 ? 0 : 1));
        const short* Ab = AldsS + rb * 4096;
        const short* Bb = BldsS + rb * 4096;
        short8 av[4], bv[4];
#pragma unroll
        for (int m = 0; m < 4; ++m)
            av[m] = *(const short8*)(Ab + (wr + m * 16 + fr) * 32 + swzr);
#pragma unroll
        for (int n = 0; n < 4; ++n)
            bv[n] = *(const short8*)(Bb + (wc + n * 16 + fr) * 32 + swzr);
        // operand order SWAPPED vs R4: first=bv, second=av -> transposed C/D roles
#pragma unroll
        for (int m = 0; m < 4; ++m)
#pragma unroll
            for (int n = 0; n < 4; ++n)
                acc[m][n] = __builtin_amdgcn_mfma_f32_16x16x32_bf16(
                    bv[n], av[m], acc[m][n], 0, 0, 0);
        rb = (rb == 2) ? 0 : rb + 1;
    }

    // ---- epilogue: bias + fast ELU + dwordx4 nontemporal stores ----
    // lane (fr,kq), fragment (m,n): row = brow*128+wr+m*16+fr,
    // cols = bcol*128+wc+n*16+kq*4+{0..3}
    const int r0 = brow * 128 + wr + fr;
    const unsigned bb0 = (unsigned)r0 / N_NODES;         // one divide per lane
    const int rsw = (int)((bb0 + 1) * N_NODES);
    float* outL = out + (size_t)(bcol >> 1) * CN;        // layer = bcol>>1 (uniform)
    const int cbase = (bcol & 1) * 128 + wc + kq * 4;    // col within layer
    f32x4 bi4[4];
#pragma unroll
    for (int n = 0; n < 4; ++n)
        bi4[n] = *(const f32x4*)(bias + bcol * 128 + wc + n * 16 + kq * 4);
#pragma unroll
    for (int m = 0; m < 4; ++m) {
        int r = r0 + m * 16;
        if (r < TOTAL) {
            int bb = (int)bb0 + (r >= rsw ? 1 : 0);
            int nn = r - bb * N_NODES;
            float* rowp = outL + (size_t)bb * OUT_STRIDE_B + (size_t)nn * C_DIM + cbase;
#pragma unroll
            for (int n = 0; n < 4; ++n) {
                f32x4 v = acc[m][n] + bi4[n];
                f32x4 o;
#pragma unroll
                for (int k = 0; k < 4; ++k)
                    o[k] = v[k] > 0.f ? v[k] : (__expf(v[k]) - 1.0f);
                __builtin_nontemporal_store(o, (f32x4*)(rowp + n * 16));
            }
        }
    }
}

extern "C" void kernel_launch(void* const* d_in, const int* in_sizes, int n_in,
                              void* d_out, int out_size, void* d_ws, size_t ws_size,
                              hipStream_t stream) {
    const float* x  = (const float*)d_in[0];
    const float* Wl = (const float*)d_in[1];
    const float* bl = (const float*)d_in[2];
    const float* Wr = (const float*)d_in[3];
    float* out = (float*)d_out;
    char* ws = (char*)d_ws;

    bf16* nodes = (bf16*)(ws + OFF_NODES);
    bf16* aggb  = (bf16*)(ws + OFF_AGGB);
    bf16* WlT   = (bf16*)(ws + OFF_WLT);
    bf16* WrT   = (bf16*)(ws + OFF_WRT);

    prep_kernel<<<128 + BATCH * 18, 256, 0, stream>>>(x, Wl, Wr, nodes, WlT, WrT, out);
    gather_kernel<<<AGG_ROWS, 256, 0, stream>>>(nodes, aggb);
    gemm_kernel<<<8 * 545, 256, 0, stream>>>(nodes, aggb, WrT, WlT, bl, out);
}

// Round 13
// 135.074 us; speedup vs baseline: 1.6724x; 1.0265x over previous
//
#include <hip/hip_runtime.h>
#include <hip/hip_bf16.h>
#include <stdint.h>

// StrideGraphSAGE on MI355X (gfx950).
// h_l = elu(agg @ Wl[l] + bl[l] + nodes @ Wr[l]); out = concat(h_0..h_3, x) along C.
// agg is nonzero only for rows < 1089; edge set = deterministic stride-2 grid.
//
// R13 = R12 (swapped-operand MFMA -> dwordx4 nt stores; 128^2, 3-ring,
// counted vmcnt(4), XCD swizzle) + ONE change: permute brow mapping
// (transpose r <-> 61r, r in [1,8]) so the 9 double-work agg-mixed brows
// spread across XCDs instead of all landing on XCD 0 (+13% -> +3% imbalance).

#define C_DIM 256
#define GRID_G 33
#define N_NODES 1089
#define BATCH 64
#define TOTAL (BATCH * N_NODES)     // 69696
#define M_PAD 69760
#define CN (C_DIM * N_NODES)        // 278784
#define OUT_STRIDE_B (5 * CN)       // 1393920
#define NCOLS 1024
#define AGG_ROWS 1152               // 9 tiles of 128; rows 1089..1151 zeroed

using bf16 = __hip_bfloat16;
typedef __attribute__((ext_vector_type(8))) short short8;
typedef __attribute__((ext_vector_type(4))) float f32x4;

// ---- workspace layout (bytes) ----
#define NODES_BYTES ((size_t)M_PAD * C_DIM * 2)
#define OFF_NODES   ((size_t)0)
#define OFF_AGGB    (NODES_BYTES)
#define AGGB_BYTES  ((size_t)AGG_ROWS * C_DIM * 2)
#define OFF_WLT     (OFF_AGGB + AGGB_BYTES)
#define WT_BYTES    ((size_t)NCOLS * C_DIM * 2)
#define OFF_WRT     (OFF_WLT + WT_BYTES)

__device__ __forceinline__ void gload16(void* lds, const void* g) {
    __builtin_amdgcn_global_load_lds(
        (const __attribute__((address_space(1))) uint32_t*)g,
        (__attribute__((address_space(3))) uint32_t*)lds,
        16, 0, 0);
}

// ---- fused prep: blocks 0..127 W->WT bf16; 128..1279: x -> nodes + out block 4 ----
__global__ __launch_bounds__(256)
void prep_kernel(const float* __restrict__ x,
                 const float* __restrict__ Wl, const float* __restrict__ Wr,
                 bf16* __restrict__ nodes, bf16* __restrict__ WlT, bf16* __restrict__ WrT,
                 float* __restrict__ out)
{
    __shared__ char smem[33792];
    const int t = threadIdx.x;
    const int bid = blockIdx.x;
    if (bid < 128) {
        float (*tile)[65] = (float(*)[65])smem;
        const int sel = bid & 1;
        const int l = (bid >> 1) & 3;
        const int kt = ((bid >> 3) & 3) * 64;
        const int ct = ((bid >> 5) & 3) * 64;
        const float* W = sel ? Wr : Wl;
        bf16* WT = sel ? WrT : WlT;
        const int tc = t & 63;
        const int tk = t >> 6;
#pragma unroll
        for (int i = 0; i < 16; ++i) {
            int kl = i * 4 + tk;
            tile[kl][tc] = W[((size_t)(l * 256 + kt + kl)) * 256 + ct + tc];
        }
        __syncthreads();
#pragma unroll
        for (int i = 0; i < 16; ++i) {
            int cl = i * 4 + tk;
            WT[((size_t)(l * 256 + ct + cl)) * 256 + kt + tc] = __float2bfloat16(tile[tc][cl]);
        }
    } else {
        bf16 (*tile)[66] = (bf16(*)[66])smem;
        const int bid2 = bid - 128;
        const int b = bid2 / 18;
        const int n0 = (bid2 % 18) * 64;
        const int nl = t & 63;
        const int cs = t >> 6;
        const int n = n0 + nl;
        const bool nvalid = n < N_NODES;
        const float* xb = x + (size_t)b * CN;
        float* outb = out + (size_t)b * OUT_STRIDE_B + (size_t)4 * CN;
#pragma unroll 4
        for (int cc = 0; cc < 64; ++cc) {
            int c = cc * 4 + cs;
            if (nvalid) {
                float v = xb[(size_t)c * N_NODES + n];
                __builtin_nontemporal_store(v, &outb[(size_t)c * N_NODES + n]);
                tile[c][nl] = __float2bfloat16(v);
            }
        }
        __syncthreads();
        const int half = t >> 7;
        const int c0 = (t & 127) * 2;
#pragma unroll
        for (int it = 0; it < 32; ++it) {
            int row = it * 2 + half;
            int nr = n0 + row;
            if (nr < N_NODES) {
                __hip_bfloat162 p;
                p.x = tile[c0][row];
                p.y = tile[c0 + 1][row];
                *(__hip_bfloat162*)(nodes + ((size_t)b * N_NODES + nr) * C_DIM + c0) = p;
            }
        }
    }
}

// ---- analytic mean-aggregate; rows N_NODES..1151 zeroed ----
__global__ __launch_bounds__(256)
void gather_kernel(const bf16* __restrict__ nodes, bf16* __restrict__ aggb)
{
    const int n = blockIdx.x;        // 0..1151
    const int c = threadIdx.x;
    if (n >= N_NODES) {
        aggb[(size_t)n * C_DIM + c] = __float2bfloat16(0.f);
        return;
    }
    const int i = n / GRID_G, j = n % GRID_G;
    float s = 0.f, d = 0.f;
    if (j >= 2)           { s += __bfloat162float(nodes[(size_t)(n - 2)  * C_DIM + c]); d += 1.f; }
    if (i >= 2)           { s += __bfloat162float(nodes[(size_t)(n - 66) * C_DIM + c]); d += 1.f; }
    if (i >= 2 && j >= 2) { s += __bfloat162float(nodes[(size_t)(n - 68) * C_DIM + c]); d += 1.f; }
    if (i >= 2 && j >= 1 && j <= 30)
                          { s += __bfloat162float(nodes[(size_t)(n - 64) * C_DIM + c]); d += 1.f; }
    aggb[(size_t)n * C_DIM + c] = __float2bfloat16(d > 0.f ? s / d : 0.f);
}

// ---- fused GEMM: out = elu(nodes@WrT^T + [agg@WlT^T] + bias), dwordx4 stores ----
// 128x128 tile, 4 waves, 16x16x32 bf16 MFMA. 3-buffer LDS, 2-deep prefetch,
// counted s_waitcnt vmcnt(4) + raw s_barrier. XOR-swizzled LDS both-sides.
// XCD-aware block swizzle + mixed-brow spreading permutation (r <-> 61r).
// MFMA operands swapped: acc[m][n] f32x4 = out[row brow*128+wr+m*16+fr]
// [cols bcol*128+wc+n*16+kq*4 .. +3] -> dwordx4 nontemporal stores.
__global__ __launch_bounds__(256)
void gemm_kernel(const bf16* __restrict__ nodes, const bf16* __restrict__ agg,
                 const bf16* __restrict__ WrT, const bf16* __restrict__ WlT,
                 const float* __restrict__ bias, float* __restrict__ out)
{
    __shared__ bf16 Alds[3][128 * 32];
    __shared__ bf16 Blds[3][128 * 32];
    const int t = threadIdx.x;
    const int lane = t & 63;
    const int w = t >> 6;
    const unsigned bid = blockIdx.x;
    const unsigned swz = (bid & 7) * 545 + (bid >> 3);
    const int bcol = swz & 7;
    int brow = (int)(swz >> 3);
    // spread the 9 agg-mixed (double-work) brows across XCDs: transpose r <-> 61r.
    // Mixed brows then sit at i in {0,61,...,488} -> XCDs {0,0,1..7} (+3% not +13%).
    if (brow >= 1 && brow <= 8) brow *= 61;
    else if (brow >= 61 && brow <= 488 && (brow % 61) == 0) brow /= 61;

    f32x4 acc[4][4] = {};

    // staging: phys 16B slot s holds logical slot s ^ ((row>>1)&3)
    const int tq = t >> 2;                               // rows 0..63 (+64 for issue 1)
    const int kk = (((t & 3) ^ ((tq >> 1) & 3)) << 3);
    const int wr = (w >> 1) << 6;
    const int wc = (w & 1) << 6;
    const int fr = lane & 15;
    const int kq = lane >> 4;
    const int swzr = (kq ^ ((fr >> 1) & 3)) << 3;        // phys slot for reads (shorts)

    char* AldsB = (char*)Alds;
    char* BldsB = (char*)Blds;
    const short* AldsS = (const short*)Alds;
    const short* BldsS = (const short*)Blds;

    const int nsteps = (brow * 128 < N_NODES) ? 16 : 8;
    const bf16* Abase0 = nodes + (size_t)brow * 128 * C_DIM;
    const bf16* Abase1 = agg + (size_t)brow * 128 * C_DIM;
    const bf16* Bbase0 = WrT + (size_t)bcol * 128 * C_DIM;
    const bf16* Bbase1 = WlT + (size_t)bcol * 128 * C_DIM;

    auto STAGE = [&](int s, int buf) {
        const int k0 = (s & 7) * 32;
        const bf16* Ag = (s < 8 ? Abase0 : Abase1) + (size_t)tq * C_DIM + k0 + kk;
        const bf16* Bg = (s < 8 ? Bbase0 : Bbase1) + (size_t)tq * C_DIM + k0 + kk;
        gload16(AldsB + buf * 8192 + w * 1024,        Ag);
        gload16(AldsB + buf * 8192 + 4096 + w * 1024, Ag + 64 * C_DIM);
        gload16(BldsB + buf * 8192 + w * 1024,        Bg);
        gload16(BldsB + buf * 8192 + 4096 + w * 1024, Bg + 64 * C_DIM);
    };

    STAGE(0, 0);
    STAGE(1, 1);                       // 8 vmem ops in flight
    int rb = 0;
    for (int s = 0; s < nsteps; ++s) {
        if (s + 1 < nsteps) asm volatile("s_waitcnt vmcnt(4)" ::: "memory");
        else                asm volatile("s_waitcnt vmcnt(0)" ::: "memory");
        __builtin_amdgcn_s_barrier();
        if (s + 2 < nsteps) STAGE(s + 2, rb == 0 ? 2 : (rb == 1 ? 0 : 1));
        const short* Ab = AldsS + rb * 4096;
        const short* Bb = BldsS + rb * 4096;
        short8 av[4], bv[4];
#pragma unroll
        for (int m = 0; m < 4; ++m)
            av[m] = *(const short8*)(Ab + (wr + m * 16 + fr) * 32 + swzr);
#pragma unroll
        for (int n = 0; n < 4; ++n)
            bv[n] = *(const short8*)(Bb + (wc + n * 16 + fr) * 32 + swzr);
        // operand order swapped: first=bv, second=av -> transposed C/D roles
#pragma unroll
        for (int m = 0; m < 4; ++m)
#pragma unroll
            for (int n = 0; n < 4; ++n)
                acc[m][n] = __builtin_amdgcn_mfma_f32_16x16x32_bf16(
                    bv[n], av[m], acc[m][n], 0, 0, 0);
        rb = (rb == 2) ? 0 : rb + 1;
    }

    // ---- epilogue: bias + fast ELU + dwordx4 nontemporal stores ----
    const int r0 = brow * 128 + wr + fr;
    const unsigned bb0 = (unsigned)r0 / N_NODES;         // one divide per lane
    const int rsw = (int)((bb0 + 1) * N_NODES);
    float* outL = out + (size_t)(bcol >> 1) * CN;        // layer = bcol>>1 (uniform)
    const int cbase = (bcol & 1) * 128 + wc + kq * 4;    // col within layer
    f32x4 bi4[4];
#pragma unroll
    for (int n = 0; n < 4; ++n)
        bi4[n] = *(const f32x4*)(bias + bcol * 128 + wc + n * 16 + kq * 4);
#pragma unroll
    for (int m = 0; m < 4; ++m) {
        int r = r0 + m * 16;
        if (r < TOTAL) {
            int bb = (int)bb0 + (r >= rsw ? 1 : 0);
            int nn = r - bb * N_NODES;
            float* rowp = outL + (size_t)bb * OUT_STRIDE_B + (size_t)nn * C_DIM + cbase;
#pragma unroll
            for (int n = 0; n < 4; ++n) {
                f32x4 v = acc[m][n] + bi4[n];
                f32x4 o;
#pragma unroll
                for (int k = 0; k < 4; ++k)
                    o[k] = v[k] > 0.f ? v[k] : (__expf(v[k]) - 1.0f);
                __builtin_nontemporal_store(o, (f32x4*)(rowp + n * 16));
            }
        }
    }
}

extern "C" void kernel_launch(void* const* d_in, const int* in_sizes, int n_in,
                              void* d_out, int out_size, void* d_ws, size_t ws_size,
                              hipStream_t stream) {
    const float* x  = (const float*)d_in[0];
    const float* Wl = (const float*)d_in[1];
    const float* bl = (const float*)d_in[2];
    const float* Wr = (const float*)d_in[3];
    float* out = (float*)d_out;
    char* ws = (char*)d_ws;

    bf16* nodes = (bf16*)(ws + OFF_NODES);
    bf16* aggb  = (bf16*)(ws + OFF_AGGB);
    bf16* WlT   = (bf16*)(ws + OFF_WLT);
    bf16* WrT   = (bf16*)(ws + OFF_WRT);

    prep_kernel<<<128 + BATCH * 18, 256, 0, stream>>>(x, Wl, Wr, nodes, WlT, WrT, out);
    gather_kernel<<<AGG_ROWS, 256, 0, stream>>>(nodes, aggb);
    gemm_kernel<<<8 * 545, 256, 0, stream>>>(nodes, aggb, WrT, WlT, bl, out);
}